// Round 3
// baseline (470.536 us; speedup 1.0000x reference)
//
#include <hip/hip_runtime.h>
#include <hip/hip_bf16.h>
#include <hip/hip_fp8.h>
#include <stdint.h>

#define B_   64
#define L_   512
#define E_   256
#define P_   64
#define KOUT 512
#define KS_  3
#define H_   512
#define T_   53
#define CINW 2688           // conv_w inner: 896*3
#define LE   516            // embp rows/batch: L + 4 (2 zero each side)
#define LPP  514            // posp rows/batch: L + 2 (1 zero each side)
#define COMW 2048           // 1536 ent + 512 sent_h

// fp8 uniform scaling: data x64, weights x64, accumulator /4096
#define FP8_S    64.0f
#define DESCALE  (1.0f / 4096.0f)

// prep-kernel grid sections
#define SEC_CW    0
#define SEC_EMBP  512
#define SEC_POSP  (SEC_EMBP + (B_ * LE / 4))     // 512 + 8256 = 8768
#define SEC_ENT   (SEC_POSP + (B_ * LPP / 4))    // 8768 + 8224 = 16992
#define SEC_POOL  (SEC_ENT + 2 * B_)             // 16992 + 128 = 17120
#define SEC_END   (SEC_POOL + 32)                // 17152

typedef __attribute__((ext_vector_type(4))) float f32x4;
typedef __attribute__((ext_vector_type(4))) int   i32x4;
typedef __attribute__((ext_vector_type(8))) int   i32x8;

__device__ __forceinline__ unsigned enc_f(float x) {
    unsigned u = __float_as_uint(x);
    return (u & 0x80000000u) ? ~u : (u | 0x80000000u);
}
__device__ __forceinline__ float dec_f(unsigned e) {
    return __uint_as_float((e & 0x80000000u) ? (e & 0x7fffffffu) : ~e);
}
__device__ __forceinline__ unsigned char f8c(float x) {
    __hip_fp8_e4m3 t(x);            // OCP e4m3fn (gfx950) — NOT fnuz
    return t.__x;
}

__device__ __forceinline__ void cp16(const void* g, void* l) {
    __builtin_amdgcn_global_load_lds(
        (const __attribute__((address_space(1))) unsigned int*)g,
        (__attribute__((address_space(3))) unsigned int*)l,
        16, 0, 0);
}

// ---------------------------------------------------------------------------
// Fused prep: 5 independent jobs selected by blockIdx.x section.
// CW section also computes corr[b][which][n] in fp32 (replaces corr_k).
// (unchanged from R7 — passed)
__global__ void prep(const float* __restrict__ conv_w,
                     const int* __restrict__ context,
                     const int* __restrict__ sidx,
                     const int* __restrict__ oidx,
                     const int* __restrict__ sdis,
                     const int* __restrict__ odis,
                     const float* __restrict__ etab,
                     const float* __restrict__ ptab,
                     unsigned char* __restrict__ wce,     // fp8, x64
                     unsigned char* __restrict__ wcp,     // fp8, x64
                     unsigned char* __restrict__ embp,    // fp8, x64
                     unsigned char* __restrict__ posp,    // fp8, x64
                     float* __restrict__ corr,            // fp32 exact
                     float* __restrict__ com,
                     unsigned* __restrict__ pooled) {
    __shared__ float w[CINW];
    const int blk = blockIdx.x;
    const int tid = threadIdx.x;

    if (blk < SEC_EMBP) {
        // ---- combine_w: one block per output channel n ----
        int n = blk;
        const float* src = conv_w + (size_t)n * CINW;
        for (int i = tid; i < CINW; i += 256) w[i] = src[i];
        __syncthreads();
        for (int i = tid; i < 5 * E_; i += 256) {
            int d = i >> 8, c = i & 255;
            float s = 0.f;
#pragma unroll
            for (int tau = 0; tau <= 2; tau++) {
                int seg = d - tau;
                if (seg >= 0 && seg <= 2) s += w[(seg * 256 + c) * 3 + tau];
            }
            wce[((size_t)d * KOUT + n) * E_ + c] = f8c(s * FP8_S);
        }
        for (int i = tid; i < 3 * 128; i += 256) {
            int tau = i >> 7, p = i & 127;
            wcp[((size_t)tau * KOUT + n) * 128 + p] = f8c(w[(768 + p) * 3 + tau] * FP8_S);
        }
        // ---- corr (fp32-exact): pair p = (b, which); 2 threads per pair ----
        {
            int p   = tid >> 1, sub = tid & 1;
            int bb  = p >> 1, which = p & 1;
            int token = context[bb * L_ + (which ? L_ - 1 : 0)];
            const float4* er4 = (const float4*)(etab + (size_t)token * E_ + sub * 128);
            int A = which ? (sub * 384 + 2) : (1536 + sub * 384);
            float s = 0.f;
#pragma unroll 8
            for (int c4 = 0; c4 < 32; c4++) {
                float4 v = er4[c4];
                int c = c4 * 4;
                s += v.x * w[A + 3 * c]     + v.y * w[A + 3 * c + 3]
                   + v.z * w[A + 3 * c + 6] + v.w * w[A + 3 * c + 9];
            }
            s += __shfl_xor(s, 1, 64);
            if (sub == 0) corr[(bb * 2 + which) * KOUT + n] = s;
        }
    } else if (blk < SEC_POSP) {
        // ---- build_embp (fp8 x64) ----
        int row = (blk - SEC_EMBP) * 4 + (tid >> 6);
        int lane = tid & 63;
        int b = row / LE, r = row % LE;
        unsigned char* out = embp + (size_t)row * E_;
        if (r < 2 || r >= LE - 2) {
            *(uchar4*)(out + lane * 4) = (uchar4){0, 0, 0, 0};
            return;
        }
        int token = context[b * L_ + (r - 2)];
        float4 v = *(const float4*)(etab + (size_t)token * E_ + lane * 4);
        uchar4 pk;
        pk.x = f8c(v.x * FP8_S); pk.y = f8c(v.y * FP8_S);
        pk.z = f8c(v.z * FP8_S); pk.w = f8c(v.w * FP8_S);
        *(uchar4*)(out + lane * 4) = pk;
    } else if (blk < SEC_ENT) {
        // ---- build_posp (fp8 x64) ----
        int row = (blk - SEC_POSP) * 4 + (tid >> 6);
        int lane = tid & 63;
        int b = row / LPP, r = row % LPP;
        unsigned char* out = posp + (size_t)row * 128;
        if (r < 1 || r >= LPP - 1) {
            *(unsigned short*)(out + lane * 2) = 0;
            return;
        }
        int l = r - 1;
        int which = lane >> 5;
        int i2 = (lane & 31) * 2;
        int t = which ? odis[b * L_ + l] : sdis[b * L_ + l];
        float2 v = *(const float2*)(ptab + (size_t)t * P_ + i2);
        unsigned short pk = (unsigned short)f8c(v.x * FP8_S)
                          | ((unsigned short)f8c(v.y * FP8_S) << 8);
        *(unsigned short*)(out + which * 64 + i2) = pk;
    } else if (blk < SEC_POOL) {
        // ---- entity_feats (fp32 exact) ----
        int idx = blk - SEC_ENT;
        int b = idx >> 1, which = idx & 1;
        const int* sp = which ? oidx : sidx;
        int s = sp[b * 2 + 0], e = sp[b * 2 + 1];
        const int* ctx = context + b * L_;
        float* outb = com + (size_t)b * COMW + which * 768;
        int d = tid;
        float sum = 0.f;
        for (int x = s; x <= e; ++x) sum += etab[(size_t)ctx[x] * E_ + d];
        outb[d] = sum / (float)(e - s + 1);
        outb[256 + d] = etab[(size_t)ctx[s - 1] * E_ + d];
        float r = 0.f;
        if (e + 1 < L_) r = etab[(size_t)ctx[e + 1] * E_ + d];
        outb[512 + d] = r;
    } else {
        // ---- zero pooled ----
        int base = ((blk - SEC_POOL) * 256 + tid) * 4;
        *(uint4*)(pooled + base) = (uint4){0, 0, 0, 0};
    }
}

// ---------------------------------------------------------------------------
// R8: B-operand in REGISTERS (global->VGPR, one tile ahead, ping-pong b0/b1
// with static indexing via full unroll); A stays in a 2x16KB LDS dbuf with the
// R6-proven XOR slot swizzle + 2-barrier/counted-vmcnt sync (no new drain
// points — R7's window-restage drains were the regression). This halves the
// LDS pipe (B's writes AND reads gone: ~53k -> ~26k cyc/CU) and moves B onto
// the otherwise-idle VMEM/L1/L2 path (wce/wcp tiles are 16KB, L1-resident;
// 2 waves/block re-read -> L1 hits). LDS 32KB + ~150 VGPR -> 3 blocks/CU of
// barrier cover. vmcnt(12) = 8 B-loads + 4 A-cp16 issued per iteration.
__global__ void __launch_bounds__(256, 3)
conv_gemm_pool(const unsigned char* __restrict__ embp,
               const unsigned char* __restrict__ posp,
               const unsigned char* __restrict__ wce,
               const unsigned char* __restrict__ wcp,
               const float* __restrict__ corr,
               unsigned* __restrict__ pooled) {
    __shared__ unsigned char sA[2][128 * 128];    // 32 KB A double-buffer

    const int tid  = threadIdx.x;
    const int lane = tid & 63;
    const int wave = tid >> 6;
    const int mt = blockIdx.x;
    const int nt = blockIdx.y;
    const int b  = mt >> 2;
    const int l0 = (mt & 3) * 128;
    const int n0 = nt * 128;

    const int wr = (wave & 1) * 64;
    const int wc = (wave >> 1) * 64;
    const int m  = lane & 15;
    const int q  = lane >> 4;

    f32x4 acc[4][4];
#pragma unroll
    for (int i = 0; i < 4; i++)
#pragma unroll
        for (int j = 0; j < 4; j++) acc[i][j] = (f32x4){0.f, 0.f, 0.f, 0.f};

    // ---- A staging: 16 KB tile = 4 cp16/thread, linear LDS dest,
    //      pre-swizzled global source (slot ^= row&7 at 16B granularity) ----
    const int srow = tid >> 3;
    const int ssw  = ((tid & 7) ^ (srow & 7)) << 4;
    auto stageA = [&](int buf, int t) {
        const unsigned char* base; int stride;
        if (t < 10) {                        // emb: (tap, kc) pairs, R6 order
            int tap = t >> 1, kc = (t & 1) << 7;
            base = embp + (size_t)(b * LE + l0 + tap) * E_ + kc;
            stride = E_;
        } else {                             // pos: tiles 10-12
            int tap = t - 10;
            base = posp + (size_t)(b * LPP + l0 + tap) * 128;
            stride = 128;
        }
        char* d = (char*)sA[buf] + tid * 16;
#pragma unroll
        for (int rnd = 0; rnd < 4; rnd++)
            cp16(base + (srow + rnd * 32) * stride + ssw, d + rnd * 4096);
    };

    // ---- B fragments: global -> registers, 2x dwordx4 per j (row wc+j*16+m,
    //      bytes [q*32, q*32+32)). No swizzle needed (no LDS round-trip). ----
    auto loadB = [&](int t, i32x8* bn) {
        const unsigned char* base; int stride;
        if (t < 10) {
            int tap = t >> 1, kc = (t & 1) << 7;
            base = wce + (size_t)(tap * KOUT + n0) * E_ + kc;
            stride = E_;
        } else {
            int tap = t - 10;
            base = wcp + (size_t)(tap * KOUT + n0) * 128;
            stride = 128;
        }
#pragma unroll
        for (int j = 0; j < 4; j++) {
            const unsigned char* rp = base + (size_t)(wc + j * 16 + m) * stride + q * 32;
            i32x4 lo = *(const i32x4*)rp;
            i32x4 hi = *(const i32x4*)(rp + 16);
            bn[j] = (i32x8){lo[0], lo[1], lo[2], lo[3], hi[0], hi[1], hi[2], hi[3]};
        }
    };

    // A fragment from LDS: lane (m,q) reads logical 16B slots 2q,2q+1 of its
    // row; physical slot = logical ^ (row&7).
    auto fragA = [&](const unsigned char* rowbase, int row) -> i32x8 {
        const unsigned char* rp = rowbase + row * 128;
        int x = (row & 7) << 4;
        i32x4 lo = *(const i32x4*)(rp + (((q << 1) << 4) ^ x));
        i32x4 hi = *(const i32x4*)(rp + ((((q << 1) | 1) << 4) ^ x));
        return (i32x8){lo[0], lo[1], lo[2], lo[3], hi[0], hi[1], hi[2], hi[3]};
    };

    auto compute = [&](int buf, i32x8* bc) {
#pragma unroll
        for (int i = 0; i < 4; i++) {        // i-outer: af single-live (8 VGPR)
            i32x8 af = fragA(sA[buf], wr + i * 16 + m);
#pragma unroll
            for (int j = 0; j < 4; j++)
                // scale bytes 0x7f (e8m0 bias 127) = exactly 1.0
                acc[i][j] = __builtin_amdgcn_mfma_scale_f32_16x16x128_f8f6f4(
                    af, bc[j], acc[i][j], 0, 0, 0, 0x7f7f7f7f, 0, 0x7f7f7f7f);
        }
    };

    i32x8 b0[4], b1[4];
    loadB(0, b0);
    stageA(0, 0);
    asm volatile("s_waitcnt vmcnt(0)" ::: "memory");
    __builtin_amdgcn_s_barrier();

#pragma unroll                               // full unroll: t, parity static
    for (int t = 0; t < 13; t++) {
        i32x8* bc = (t & 1) ? b1 : b0;
        i32x8* bn = (t & 1) ? b0 : b1;
        if (t < 12) {
            loadB(t + 1, bn);                // 8 VMEM
            stageA((t + 1) & 1, t + 1);      // 4 VMEM (lds)
            asm volatile("s_waitcnt vmcnt(12)" ::: "memory");  // tile t landed
        } else {
            asm volatile("s_waitcnt vmcnt(0)" ::: "memory");
        }
        __builtin_amdgcn_s_barrier();        // A(t) visible to all waves
        __builtin_amdgcn_sched_barrier(0);
        compute(t & 1, bc);
        __builtin_amdgcn_sched_barrier(0);
        __builtin_amdgcn_s_barrier();        // A(t) consumed by all waves
    }

    const float* corrb = corr + b * 2 * KOUT;
#pragma unroll
    for (int j = 0; j < 4; j++) {
        int col = n0 + wc + j * 16 + m;
        float mx = -3.4e38f;
#pragma unroll
        for (int i = 0; i < 4; i++)
#pragma unroll
            for (int r = 0; r < 4; r++) {
                float v = acc[i][j][r] * DESCALE;
                int l = l0 + wr + i * 16 + q * 4 + r;
                if (l == 0)      v -= corrb[col];
                if (l == L_ - 1) v -= corrb[KOUT + col];
                mx = fmaxf(mx, v);
            }
        mx = fmaxf(mx, __shfl_xor(mx, 16, 64));
        mx = fmaxf(mx, __shfl_xor(mx, 32, 64));
        if (q == 0) atomicMax(&pooled[b * KOUT + col], enc_f(mx));
    }
}

// ---------------------------------------------------------------------------
__global__ void lin1_k(const unsigned* __restrict__ pooled,
                       const float* __restrict__ conv_b,
                       const float* __restrict__ lin1_w,
                       const float* __restrict__ lin1_b,
                       float* __restrict__ com) {
    int bid = blockIdx.x;
    int wave = threadIdx.x >> 6, lane = threadIdx.x & 63;
    int b = bid >> 7;
    int h = (bid & 127) * 4 + wave;
    const float* w = lin1_w + (size_t)h * KOUT;
    const unsigned* pb = pooled + b * KOUT;
    float s = 0.f;
#pragma unroll
    for (int i = 0; i < 8; i++) {
        int k = lane + 64 * i;
        s += (dec_f(pb[k]) + conv_b[k]) * w[k];
    }
#pragma unroll
    for (int off = 32; off > 0; off >>= 1) s += __shfl_down(s, off, 64);
    if (lane == 0) com[(size_t)b * COMW + 1536 + h] = tanhf(s + lin1_b[h]);
}

__global__ void lin2_k(const float* __restrict__ com,
                       const float* __restrict__ lin2_w,
                       const float* __restrict__ lin2_b,
                       float* __restrict__ out) {
    int b = blockIdx.x;
    int wave = threadIdx.x >> 6, lane = threadIdx.x & 63;
    int t = blockIdx.y * 4 + wave;
    if (t >= T_) return;
    const float* w = lin2_w + (size_t)t * COMW;
    const float* c = com + (size_t)b * COMW;
    float s = 0.f;
#pragma unroll
    for (int i = 0; i < 32; i++) {
        int k = lane + 64 * i;
        s += c[k] * w[k];
    }
#pragma unroll
    for (int off = 32; off > 0; off >>= 1) s += __shfl_down(s, off, 64);
    if (lane == 0) out[b * T_ + t] = s + lin2_b[t];
}

// ---------------------------------------------------------------------------
extern "C" void kernel_launch(void* const* d_in, const int* in_sizes, int n_in,
                              void* d_out, int out_size, void* d_ws, size_t ws_size,
                              hipStream_t stream) {
    const int*   context = (const int*)d_in[0];
    const int*   sidx    = (const int*)d_in[1];
    const int*   oidx    = (const int*)d_in[2];
    const int*   sdis    = (const int*)d_in[3];
    const int*   odis    = (const int*)d_in[4];
    const float* etab    = (const float*)d_in[5];
    const float* ptab    = (const float*)d_in[6];
    const float* conv_w  = (const float*)d_in[7];
    const float* conv_b  = (const float*)d_in[8];
    const float* lin1_w  = (const float*)d_in[9];
    const float* lin1_b  = (const float*)d_in[10];
    const float* lin2_w  = (const float*)d_in[11];
    const float* lin2_b  = (const float*)d_in[12];
    float* out = (float*)d_out;

    char* ws = (char*)d_ws;
    size_t off = 0;
    unsigned char* embp = (unsigned char*)(ws + off);
    off += (size_t)B_ * LE * E_;                 // 8.45 MB (fp8)
    off = (off + 255) & ~(size_t)255;
    unsigned char* posp = (unsigned char*)(ws + off);
    off += (size_t)B_ * LPP * 128;               // 4.2 MB (fp8)
    off = (off + 255) & ~(size_t)255;
    unsigned char* wce = (unsigned char*)(ws + off);
    off += (size_t)5 * KOUT * E_;                // 655 KB (fp8)
    off = (off + 255) & ~(size_t)255;
    unsigned char* wcp = (unsigned char*)(ws + off);
    off += (size_t)3 * KOUT * 128;               // 197 KB (fp8)
    off = (off + 255) & ~(size_t)255;
    float* corr = (float*)(ws + off);
    off += (size_t)B_ * 2 * KOUT * 4;            // 256 KB
    off = (off + 255) & ~(size_t)255;
    unsigned* pooled = (unsigned*)(ws + off);
    off += (size_t)B_ * KOUT * 4;                // 128 KB
    off = (off + 255) & ~(size_t)255;
    float* com = (float*)(ws + off);
    off += (size_t)B_ * COMW * 4;                // 512 KB

    prep<<<dim3(SEC_END), dim3(256), 0, stream>>>(
        conv_w, context, sidx, oidx, sdis, odis, etab, ptab,
        wce, wcp, embp, posp, corr, com, pooled);
    conv_gemm_pool<<<dim3(256, 4), dim3(256), 0, stream>>>(embp, posp, wce, wcp, corr, pooled);
    lin1_k<<<dim3(8192), dim3(256), 0, stream>>>(pooled, conv_b, lin1_w, lin1_b, com);
    lin2_k<<<dim3(B_, 14), dim3(256), 0, stream>>>(com, lin2_w, lin2_b, out);
}

// Round 4
// 190.324 us; speedup vs baseline: 2.4723x; 2.4723x over previous
//
#include <hip/hip_runtime.h>
#include <hip/hip_bf16.h>
#include <hip/hip_fp8.h>
#include <stdint.h>

#define B_   64
#define L_   512
#define E_   256
#define P_   64
#define KOUT 512
#define KS_  3
#define H_   512
#define T_   53
#define CINW 2688           // conv_w inner: 896*3
#define LE   516            // embp rows/batch: L + 4 (2 zero each side)
#define LPP  514            // posp rows/batch: L + 2 (1 zero each side)
#define COMW 2048           // 1536 ent + 512 sent_h

// fp8 uniform scaling: data x64, weights x64, accumulator /4096
#define FP8_S    64.0f
#define DESCALE  (1.0f / 4096.0f)

// prep-kernel grid sections
#define SEC_CW    0
#define SEC_EMBP  512
#define SEC_POSP  (SEC_EMBP + (B_ * LE / 4))     // 512 + 8256 = 8768
#define SEC_ENT   (SEC_POSP + (B_ * LPP / 4))    // 8768 + 8224 = 16992
#define SEC_POOL  (SEC_ENT + 2 * B_)             // 16992 + 128 = 17120
#define SEC_END   (SEC_POOL + 32)                // 17152

typedef __attribute__((ext_vector_type(4))) float f32x4;
typedef __attribute__((ext_vector_type(4))) int   i32x4;
typedef __attribute__((ext_vector_type(8))) int   i32x8;

__device__ __forceinline__ unsigned enc_f(float x) {
    unsigned u = __float_as_uint(x);
    return (u & 0x80000000u) ? ~u : (u | 0x80000000u);
}
__device__ __forceinline__ float dec_f(unsigned e) {
    return __uint_as_float((e & 0x80000000u) ? (e & 0x7fffffffu) : ~e);
}
__device__ __forceinline__ unsigned char f8c(float x) {
    __hip_fp8_e4m3 t(x);            // OCP e4m3fn (gfx950) — NOT fnuz
    return t.__x;
}

__device__ __forceinline__ void cp16(const void* g, void* l) {
    __builtin_amdgcn_global_load_lds(
        (const __attribute__((address_space(1))) unsigned int*)g,
        (__attribute__((address_space(3))) unsigned int*)l,
        16, 0, 0);
}

// ---------------------------------------------------------------------------
// Fused prep: 5 independent jobs selected by blockIdx.x section.
// CW section also computes corr[b][which][n] in fp32 (replaces corr_k).
// (unchanged from R7 — passed)
__global__ void prep(const float* __restrict__ conv_w,
                     const int* __restrict__ context,
                     const int* __restrict__ sidx,
                     const int* __restrict__ oidx,
                     const int* __restrict__ sdis,
                     const int* __restrict__ odis,
                     const float* __restrict__ etab,
                     const float* __restrict__ ptab,
                     unsigned char* __restrict__ wce,     // fp8, x64
                     unsigned char* __restrict__ wcp,     // fp8, x64
                     unsigned char* __restrict__ embp,    // fp8, x64
                     unsigned char* __restrict__ posp,    // fp8, x64
                     float* __restrict__ corr,            // fp32 exact
                     float* __restrict__ com,
                     unsigned* __restrict__ pooled) {
    __shared__ float w[CINW];
    const int blk = blockIdx.x;
    const int tid = threadIdx.x;

    if (blk < SEC_EMBP) {
        // ---- combine_w: one block per output channel n ----
        int n = blk;
        const float* src = conv_w + (size_t)n * CINW;
        for (int i = tid; i < CINW; i += 256) w[i] = src[i];
        __syncthreads();
        for (int i = tid; i < 5 * E_; i += 256) {
            int d = i >> 8, c = i & 255;
            float s = 0.f;
#pragma unroll
            for (int tau = 0; tau <= 2; tau++) {
                int seg = d - tau;
                if (seg >= 0 && seg <= 2) s += w[(seg * 256 + c) * 3 + tau];
            }
            wce[((size_t)d * KOUT + n) * E_ + c] = f8c(s * FP8_S);
        }
        for (int i = tid; i < 3 * 128; i += 256) {
            int tau = i >> 7, p = i & 127;
            wcp[((size_t)tau * KOUT + n) * 128 + p] = f8c(w[(768 + p) * 3 + tau] * FP8_S);
        }
        // ---- corr (fp32-exact): pair p = (b, which); 2 threads per pair ----
        {
            int p   = tid >> 1, sub = tid & 1;
            int bb  = p >> 1, which = p & 1;
            int token = context[bb * L_ + (which ? L_ - 1 : 0)];
            const float4* er4 = (const float4*)(etab + (size_t)token * E_ + sub * 128);
            int A = which ? (sub * 384 + 2) : (1536 + sub * 384);
            float s = 0.f;
#pragma unroll 8
            for (int c4 = 0; c4 < 32; c4++) {
                float4 v = er4[c4];
                int c = c4 * 4;
                s += v.x * w[A + 3 * c]     + v.y * w[A + 3 * c + 3]
                   + v.z * w[A + 3 * c + 6] + v.w * w[A + 3 * c + 9];
            }
            s += __shfl_xor(s, 1, 64);
            if (sub == 0) corr[(bb * 2 + which) * KOUT + n] = s;
        }
    } else if (blk < SEC_POSP) {
        // ---- build_embp (fp8 x64) ----
        int row = (blk - SEC_EMBP) * 4 + (tid >> 6);
        int lane = tid & 63;
        int b = row / LE, r = row % LE;
        unsigned char* out = embp + (size_t)row * E_;
        if (r < 2 || r >= LE - 2) {
            *(uchar4*)(out + lane * 4) = (uchar4){0, 0, 0, 0};
            return;
        }
        int token = context[b * L_ + (r - 2)];
        float4 v = *(const float4*)(etab + (size_t)token * E_ + lane * 4);
        uchar4 pk;
        pk.x = f8c(v.x * FP8_S); pk.y = f8c(v.y * FP8_S);
        pk.z = f8c(v.z * FP8_S); pk.w = f8c(v.w * FP8_S);
        *(uchar4*)(out + lane * 4) = pk;
    } else if (blk < SEC_ENT) {
        // ---- build_posp (fp8 x64) ----
        int row = (blk - SEC_POSP) * 4 + (tid >> 6);
        int lane = tid & 63;
        int b = row / LPP, r = row % LPP;
        unsigned char* out = posp + (size_t)row * 128;
        if (r < 1 || r >= LPP - 1) {
            *(unsigned short*)(out + lane * 2) = 0;
            return;
        }
        int l = r - 1;
        int which = lane >> 5;
        int i2 = (lane & 31) * 2;
        int t = which ? odis[b * L_ + l] : sdis[b * L_ + l];
        float2 v = *(const float2*)(ptab + (size_t)t * P_ + i2);
        unsigned short pk = (unsigned short)f8c(v.x * FP8_S)
                          | ((unsigned short)f8c(v.y * FP8_S) << 8);
        *(unsigned short*)(out + which * 64 + i2) = pk;
    } else if (blk < SEC_POOL) {
        // ---- entity_feats (fp32 exact) ----
        int idx = blk - SEC_ENT;
        int b = idx >> 1, which = idx & 1;
        const int* sp = which ? oidx : sidx;
        int s = sp[b * 2 + 0], e = sp[b * 2 + 1];
        const int* ctx = context + b * L_;
        float* outb = com + (size_t)b * COMW + which * 768;
        int d = tid;
        float sum = 0.f;
        for (int x = s; x <= e; ++x) sum += etab[(size_t)ctx[x] * E_ + d];
        outb[d] = sum / (float)(e - s + 1);
        outb[256 + d] = etab[(size_t)ctx[s - 1] * E_ + d];
        float r = 0.f;
        if (e + 1 < L_) r = etab[(size_t)ctx[e + 1] * E_ + d];
        outb[512 + d] = r;
    } else {
        // ---- zero pooled ----
        int base = ((blk - SEC_POOL) * 256 + tid) * 4;
        *(uint4*)(pooled + base) = (uint4){0, 0, 0, 0};
    }
}

// ---------------------------------------------------------------------------
// conv GEMM: VERBATIM the R6 kernel that measured in the 181.4 µs run
// (MX-scaled fp8 K=128, 128B rows, 8-slot XOR swizzle, 2x32KB dbuf,
// counted vmcnt(8)). R8's B-in-registers attempt hit rule #20 (ping-pong
// arrays -> scratch, 540 MB scratch writes); reverted to the proven bytes.
__global__ void __launch_bounds__(256, 2)
conv_gemm_pool(const unsigned char* __restrict__ embp,
               const unsigned char* __restrict__ posp,
               const unsigned char* __restrict__ wce,
               const unsigned char* __restrict__ wcp,
               const float* __restrict__ corr,
               unsigned* __restrict__ pooled) {
    __shared__ unsigned char sT[2][2][128 * 128];

    const int tid  = threadIdx.x;
    const int lane = tid & 63;
    const int wave = tid >> 6;
    const int mt = blockIdx.x;
    const int nt = blockIdx.y;
    const int b  = mt >> 2;
    const int l0 = (mt & 3) * 128;
    const int n0 = nt * 128;

    const int wr = (wave & 1) * 64;
    const int wc = (wave >> 1) * 64;
    const int m  = lane & 15;
    const int q  = lane >> 4;

    f32x4 acc[4][4];
#pragma unroll
    for (int i = 0; i < 4; i++)
#pragma unroll
        for (int j = 0; j < 4; j++) acc[i][j] = (f32x4){0.f, 0.f, 0.f, 0.f};

    const int srow = tid >> 3;                       // row within round
    const int ssw  = ((tid & 7) ^ (srow & 7)) << 4;  // swizzled source slot

    auto bases = [&](int t, const char*& A, int& As, const char*& Bx, int& Bs) {
        if (t < 10) {            // emb phase: 5 taps x 2 K-chunks of 128B
            int tap = t >> 1, kc = (t & 1) << 7;
            A  = (const char*)embp + ((size_t)(b * LE + l0 + tap) << 8) + kc;
            As = E_;
            Bx = (const char*)wce + ((size_t)(tap * KOUT + n0) << 8) + kc;
            Bs = E_;
        } else {                 // pos phase: 3 taps x 1 chunk
            int tap = t - 10;
            A  = (const char*)posp + ((size_t)(b * LPP + l0 + tap) << 7);
            As = 128;
            Bx = (const char*)wcp + ((size_t)(tap * KOUT + n0) << 7);
            Bs = 128;
        }
    };

    auto stage = [&](int bf_, const char* A, int As, const char* Bx, int Bs) {
        char* dA = (char*)&sT[bf_][0][0] + tid * 16;
        char* dB = (char*)&sT[bf_][1][0] + tid * 16;
#pragma unroll
        for (int rnd = 0; rnd < 4; rnd++) {          // 8 global_load_lds / wave
            int r = srow + rnd * 32;                 // (r&7)==(srow&7)
            cp16(A  + r * As + ssw, dA + rnd * 4096);
            cp16(Bx + r * Bs + ssw, dB + rnd * 4096);
        }
    };

    auto frag = [&](const unsigned char* base, int row) -> i32x8 {
        const unsigned char* rp = base + row * 128;
        int x  = (row & 7) << 4;
        i32x4 lo = *(const i32x4*)(rp + (((q << 1) << 4) ^ x));
        i32x4 hi = *(const i32x4*)(rp + ((((q << 1) | 1) << 4) ^ x));
        return (i32x8){lo[0], lo[1], lo[2], lo[3], hi[0], hi[1], hi[2], hi[3]};
    };

    auto compute = [&](int bf_) {
        const unsigned char* pA = &sT[bf_][0][0];
        const unsigned char* pB = &sT[bf_][1][0];
        i32x8 af[4];
#pragma unroll
        for (int i = 0; i < 4; i++) af[i] = frag(pA, wr + i * 16 + m);
#pragma unroll
        for (int j = 0; j < 4; j++) {
            i32x8 bfv = frag(pB, wc + j * 16 + m);
#pragma unroll
            for (int i = 0; i < 4; i++)
                // scale bytes 0x7f (e8m0 bias 127) = exactly 1.0
                acc[i][j] = __builtin_amdgcn_mfma_scale_f32_16x16x128_f8f6f4(
                    af[i], bfv, acc[i][j], 0, 0, 0, 0x7f7f7f7f, 0, 0x7f7f7f7f);
        }
    };

    // 2-phase pipeline: 13 K=128 tiles
    {
        const char *A0, *B0; int As0, Bs0;
        bases(0, A0, As0, B0, Bs0);
        stage(0, A0, As0, B0, Bs0);
    }
    int cur = 0;
#pragma unroll 1
    for (int t = 0; t < 13; t++) {
        if (t < 12) {
            const char *A1, *B1; int As1, Bs1;
            bases(t + 1, A1, As1, B1, Bs1);
            stage(cur ^ 1, A1, As1, B1, Bs1);
            // wait only the 8 older loads (tile t); tile t+1's 8 stay in flight
            asm volatile("s_waitcnt vmcnt(8)" ::: "memory");
        } else {
            asm volatile("s_waitcnt vmcnt(0)" ::: "memory");
        }
        __builtin_amdgcn_s_barrier();          // tile t ready for all waves
        __builtin_amdgcn_sched_barrier(0);     // pin: no ds_read hoists above
        compute(cur);
        __builtin_amdgcn_sched_barrier(0);
        __builtin_amdgcn_s_barrier();          // tile t consumed by all waves
        cur ^= 1;
    }

    const float* corrb = corr + b * 2 * KOUT;
#pragma unroll
    for (int j = 0; j < 4; j++) {
        int col = n0 + wc + j * 16 + m;
        float mx = -3.4e38f;
#pragma unroll
        for (int i = 0; i < 4; i++)
#pragma unroll
            for (int r = 0; r < 4; r++) {
                float v = acc[i][j][r] * DESCALE;
                int l = l0 + wr + i * 16 + q * 4 + r;
                if (l == 0)      v -= corrb[col];
                if (l == L_ - 1) v -= corrb[KOUT + col];
                mx = fmaxf(mx, v);
            }
        mx = fmaxf(mx, __shfl_xor(mx, 16, 64));
        mx = fmaxf(mx, __shfl_xor(mx, 32, 64));
        if (q == 0) atomicMax(&pooled[b * KOUT + col], enc_f(mx));
    }
}

// ---------------------------------------------------------------------------
// R9: lin1+lin2 fused — one block per batch row, 1024 threads (16 waves).
// sent_h lives in LDS only (never round-trips global). Phase 1: wave w
// computes h = w*32+hh via the proven coalesced stride-64 dot + shfl reduce.
// Phase 2: wave w computes scores t = w, w+16, ... reading ent-features from
// com (global, coalesced) and sent_h from LDS. Removes one launch (~10 µs
// overhead) + the com[1536..2048] write/read round-trip.
__global__ void lin_fused(const unsigned* __restrict__ pooled,
                          const float* __restrict__ conv_b,
                          const float* __restrict__ lin1_w,
                          const float* __restrict__ lin1_b,
                          const float* __restrict__ com,
                          const float* __restrict__ lin2_w,
                          const float* __restrict__ lin2_b,
                          float* __restrict__ out) {
    __shared__ float padj[KOUT];   // dec(pooled) + conv_b
    __shared__ float sh[H_];       // sent_h
    const int b    = blockIdx.x;
    const int tid  = threadIdx.x;
    const int wave = tid >> 6, lane = tid & 63;

    if (tid < KOUT) padj[tid] = dec_f(pooled[b * KOUT + tid]) + conv_b[tid];
    __syncthreads();

    // phase 1: sent_h (each wave: 32 sequential h)
#pragma unroll 1
    for (int hh = 0; hh < 32; ++hh) {
        int h = wave * 32 + hh;
        const float* w = lin1_w + (size_t)h * KOUT;
        float s = 0.f;
#pragma unroll
        for (int i = 0; i < 8; i++) {
            int k = lane + 64 * i;
            s += padj[k] * w[k];
        }
#pragma unroll
        for (int off = 32; off > 0; off >>= 1) s += __shfl_down(s, off, 64);
        if (lane == 0) sh[h] = tanhf(s + lin1_b[h]);
    }
    __syncthreads();

    // phase 2: scores
    const float* c = com + (size_t)b * COMW;     // first 1536 entries used
#pragma unroll 1
    for (int t = wave; t < T_; t += 16) {
        const float* w = lin2_w + (size_t)t * COMW;
        float s = 0.f;
#pragma unroll
        for (int i = 0; i < 24; i++) {           // ent features from global
            int j = lane + 64 * i;
            s += c[j] * w[j];
        }
#pragma unroll
        for (int i = 24; i < 32; i++) {          // sent_h from LDS
            int j = lane + 64 * i;
            s += sh[j - 1536] * w[j];
        }
#pragma unroll
        for (int off = 32; off > 0; off >>= 1) s += __shfl_down(s, off, 64);
        if (lane == 0) out[b * T_ + t] = s + lin2_b[t];
    }
}

// ---------------------------------------------------------------------------
extern "C" void kernel_launch(void* const* d_in, const int* in_sizes, int n_in,
                              void* d_out, int out_size, void* d_ws, size_t ws_size,
                              hipStream_t stream) {
    const int*   context = (const int*)d_in[0];
    const int*   sidx    = (const int*)d_in[1];
    const int*   oidx    = (const int*)d_in[2];
    const int*   sdis    = (const int*)d_in[3];
    const int*   odis    = (const int*)d_in[4];
    const float* etab    = (const float*)d_in[5];
    const float* ptab    = (const float*)d_in[6];
    const float* conv_w  = (const float*)d_in[7];
    const float* conv_b  = (const float*)d_in[8];
    const float* lin1_w  = (const float*)d_in[9];
    const float* lin1_b  = (const float*)d_in[10];
    const float* lin2_w  = (const float*)d_in[11];
    const float* lin2_b  = (const float*)d_in[12];
    float* out = (float*)d_out;

    char* ws = (char*)d_ws;
    size_t off = 0;
    unsigned char* embp = (unsigned char*)(ws + off);
    off += (size_t)B_ * LE * E_;                 // 8.45 MB (fp8)
    off = (off + 255) & ~(size_t)255;
    unsigned char* posp = (unsigned char*)(ws + off);
    off += (size_t)B_ * LPP * 128;               // 4.2 MB (fp8)
    off = (off + 255) & ~(size_t)255;
    unsigned char* wce = (unsigned char*)(ws + off);
    off += (size_t)5 * KOUT * E_;                // 655 KB (fp8)
    off = (off + 255) & ~(size_t)255;
    unsigned char* wcp = (unsigned char*)(ws + off);
    off += (size_t)3 * KOUT * 128;               // 197 KB (fp8)
    off = (off + 255) & ~(size_t)255;
    float* corr = (float*)(ws + off);
    off += (size_t)B_ * 2 * KOUT * 4;            // 256 KB
    off = (off + 255) & ~(size_t)255;
    unsigned* pooled = (unsigned*)(ws + off);
    off += (size_t)B_ * KOUT * 4;                // 128 KB
    off = (off + 255) & ~(size_t)255;
    float* com = (float*)(ws + off);
    off += (size_t)B_ * COMW * 4;                // 512 KB

    prep<<<dim3(SEC_END), dim3(256), 0, stream>>>(
        conv_w, context, sidx, oidx, sdis, odis, etab, ptab,
        wce, wcp, embp, posp, corr, com, pooled);
    conv_gemm_pool<<<dim3(256, 4), dim3(256), 0, stream>>>(embp, posp, wce, wcp, corr, pooled);
    lin_fused<<<dim3(B_), dim3(1024), 0, stream>>>(
        pooled, conv_b, lin1_w, lin1_b, com, lin2_w, lin2_b, out);
}

// Round 5
// 178.910 us; speedup vs baseline: 2.6300x; 1.0638x over previous
//
#include <hip/hip_runtime.h>
#include <hip/hip_bf16.h>
#include <hip/hip_fp8.h>
#include <stdint.h>

#define B_   64
#define L_   512
#define E_   256
#define P_   64
#define KOUT 512
#define KS_  3
#define H_   512
#define T_   53
#define CINW 2688           // conv_w inner: 896*3
#define LE   516            // embp rows/batch: L + 4 (2 zero each side)
#define LPP  514            // posp rows/batch: L + 2 (1 zero each side)
#define COMW 2048           // 1536 ent + 512 sent_h

// fp8 uniform scaling: data x64, weights x64, accumulator /4096
#define FP8_S    64.0f
#define DESCALE  (1.0f / 4096.0f)

// prep-kernel grid sections
#define SEC_CW    0
#define SEC_EMBP  512
#define SEC_POSP  (SEC_EMBP + (B_ * LE / 4))     // 512 + 8256 = 8768
#define SEC_ENT   (SEC_POSP + (B_ * LPP / 4))    // 8768 + 8224 = 16992
#define SEC_POOL  (SEC_ENT + 2 * B_)             // 16992 + 128 = 17120
#define SEC_END   (SEC_POOL + 32)                // 17152

typedef __attribute__((ext_vector_type(4))) float f32x4;
typedef __attribute__((ext_vector_type(4))) int   i32x4;
typedef __attribute__((ext_vector_type(8))) int   i32x8;

__device__ __forceinline__ unsigned enc_f(float x) {
    unsigned u = __float_as_uint(x);
    return (u & 0x80000000u) ? ~u : (u | 0x80000000u);
}
__device__ __forceinline__ float dec_f(unsigned e) {
    return __uint_as_float((e & 0x80000000u) ? (e & 0x7fffffffu) : ~e);
}
__device__ __forceinline__ unsigned char f8c(float x) {
    __hip_fp8_e4m3 t(x);            // OCP e4m3fn (gfx950) — NOT fnuz
    return t.__x;
}

__device__ __forceinline__ void cp16(const void* g, void* l) {
    __builtin_amdgcn_global_load_lds(
        (const __attribute__((address_space(1))) unsigned int*)g,
        (__attribute__((address_space(3))) unsigned int*)l,
        16, 0, 0);
}

// ---------------------------------------------------------------------------
// Fused prep: 5 independent jobs selected by blockIdx.x section.
// CW section also computes corr[b][which][n] in fp32 (replaces corr_k).
// (passed R2/R4, absmax unchanged)
__global__ void prep(const float* __restrict__ conv_w,
                     const int* __restrict__ context,
                     const int* __restrict__ sidx,
                     const int* __restrict__ oidx,
                     const int* __restrict__ sdis,
                     const int* __restrict__ odis,
                     const float* __restrict__ etab,
                     const float* __restrict__ ptab,
                     unsigned char* __restrict__ wce,     // fp8, x64
                     unsigned char* __restrict__ wcp,     // fp8, x64
                     unsigned char* __restrict__ embp,    // fp8, x64
                     unsigned char* __restrict__ posp,    // fp8, x64
                     float* __restrict__ corr,            // fp32 exact
                     float* __restrict__ com,
                     unsigned* __restrict__ pooled) {
    __shared__ float w[CINW];
    const int blk = blockIdx.x;
    const int tid = threadIdx.x;

    if (blk < SEC_EMBP) {
        // ---- combine_w: one block per output channel n ----
        int n = blk;
        const float* src = conv_w + (size_t)n * CINW;
        for (int i = tid; i < CINW; i += 256) w[i] = src[i];
        __syncthreads();
        for (int i = tid; i < 5 * E_; i += 256) {
            int d = i >> 8, c = i & 255;
            float s = 0.f;
#pragma unroll
            for (int tau = 0; tau <= 2; tau++) {
                int seg = d - tau;
                if (seg >= 0 && seg <= 2) s += w[(seg * 256 + c) * 3 + tau];
            }
            wce[((size_t)d * KOUT + n) * E_ + c] = f8c(s * FP8_S);
        }
        for (int i = tid; i < 3 * 128; i += 256) {
            int tau = i >> 7, p = i & 127;
            wcp[((size_t)tau * KOUT + n) * 128 + p] = f8c(w[(768 + p) * 3 + tau] * FP8_S);
        }
        // ---- corr (fp32-exact): pair p = (b, which); 2 threads per pair ----
        {
            int p   = tid >> 1, sub = tid & 1;
            int bb  = p >> 1, which = p & 1;
            int token = context[bb * L_ + (which ? L_ - 1 : 0)];
            const float4* er4 = (const float4*)(etab + (size_t)token * E_ + sub * 128);
            int A = which ? (sub * 384 + 2) : (1536 + sub * 384);
            float s = 0.f;
#pragma unroll 8
            for (int c4 = 0; c4 < 32; c4++) {
                float4 v = er4[c4];
                int c = c4 * 4;
                s += v.x * w[A + 3 * c]     + v.y * w[A + 3 * c + 3]
                   + v.z * w[A + 3 * c + 6] + v.w * w[A + 3 * c + 9];
            }
            s += __shfl_xor(s, 1, 64);
            if (sub == 0) corr[(bb * 2 + which) * KOUT + n] = s;
        }
    } else if (blk < SEC_POSP) {
        // ---- build_embp (fp8 x64) ----
        int row = (blk - SEC_EMBP) * 4 + (tid >> 6);
        int lane = tid & 63;
        int b = row / LE, r = row % LE;
        unsigned char* out = embp + (size_t)row * E_;
        if (r < 2 || r >= LE - 2) {
            *(uchar4*)(out + lane * 4) = (uchar4){0, 0, 0, 0};
            return;
        }
        int token = context[b * L_ + (r - 2)];
        float4 v = *(const float4*)(etab + (size_t)token * E_ + lane * 4);
        uchar4 pk;
        pk.x = f8c(v.x * FP8_S); pk.y = f8c(v.y * FP8_S);
        pk.z = f8c(v.z * FP8_S); pk.w = f8c(v.w * FP8_S);
        *(uchar4*)(out + lane * 4) = pk;
    } else if (blk < SEC_ENT) {
        // ---- build_posp (fp8 x64) ----
        int row = (blk - SEC_POSP) * 4 + (tid >> 6);
        int lane = tid & 63;
        int b = row / LPP, r = row % LPP;
        unsigned char* out = posp + (size_t)row * 128;
        if (r < 1 || r >= LPP - 1) {
            *(unsigned short*)(out + lane * 2) = 0;
            return;
        }
        int l = r - 1;
        int which = lane >> 5;
        int i2 = (lane & 31) * 2;
        int t = which ? odis[b * L_ + l] : sdis[b * L_ + l];
        float2 v = *(const float2*)(ptab + (size_t)t * P_ + i2);
        unsigned short pk = (unsigned short)f8c(v.x * FP8_S)
                          | ((unsigned short)f8c(v.y * FP8_S) << 8);
        *(unsigned short*)(out + which * 64 + i2) = pk;
    } else if (blk < SEC_POOL) {
        // ---- entity_feats (fp32 exact) ----
        int idx = blk - SEC_ENT;
        int b = idx >> 1, which = idx & 1;
        const int* sp = which ? oidx : sidx;
        int s = sp[b * 2 + 0], e = sp[b * 2 + 1];
        const int* ctx = context + b * L_;
        float* outb = com + (size_t)b * COMW + which * 768;
        int d = tid;
        float sum = 0.f;
        for (int x = s; x <= e; ++x) sum += etab[(size_t)ctx[x] * E_ + d];
        outb[d] = sum / (float)(e - s + 1);
        outb[256 + d] = etab[(size_t)ctx[s - 1] * E_ + d];
        float r = 0.f;
        if (e + 1 < L_) r = etab[(size_t)ctx[e + 1] * E_ + d];
        outb[512 + d] = r;
    } else {
        // ---- zero pooled (atomicMax baseline; enc of any real value > 0) ----
        int base = ((blk - SEC_POOL) * 256 + tid) * 4;
        *(uint4*)(pooled + base) = (uint4){0, 0, 0, 0};
    }
}

// ---------------------------------------------------------------------------
// conv GEMM: VERBATIM the R6 kernel from the 181.4 µs run (MX-scaled fp8
// K=128, 128B rows, 8-slot XOR swizzle, 2x32KB dbuf, counted vmcnt(8)).
// Do not touch: both attempted "improvements" (R7 window, R8 B-in-regs)
// regressed; this is the proven local optimum of the 2-phase structure.
__global__ void __launch_bounds__(256, 2)
conv_gemm_pool(const unsigned char* __restrict__ embp,
               const unsigned char* __restrict__ posp,
               const unsigned char* __restrict__ wce,
               const unsigned char* __restrict__ wcp,
               const float* __restrict__ corr,
               unsigned* __restrict__ pooled) {
    __shared__ unsigned char sT[2][2][128 * 128];

    const int tid  = threadIdx.x;
    const int lane = tid & 63;
    const int wave = tid >> 6;
    const int mt = blockIdx.x;
    const int nt = blockIdx.y;
    const int b  = mt >> 2;
    const int l0 = (mt & 3) * 128;
    const int n0 = nt * 128;

    const int wr = (wave & 1) * 64;
    const int wc = (wave >> 1) * 64;
    const int m  = lane & 15;
    const int q  = lane >> 4;

    f32x4 acc[4][4];
#pragma unroll
    for (int i = 0; i < 4; i++)
#pragma unroll
        for (int j = 0; j < 4; j++) acc[i][j] = (f32x4){0.f, 0.f, 0.f, 0.f};

    const int srow = tid >> 3;                       // row within round
    const int ssw  = ((tid & 7) ^ (srow & 7)) << 4;  // swizzled source slot

    auto bases = [&](int t, const char*& A, int& As, const char*& Bx, int& Bs) {
        if (t < 10) {            // emb phase: 5 taps x 2 K-chunks of 128B
            int tap = t >> 1, kc = (t & 1) << 7;
            A  = (const char*)embp + ((size_t)(b * LE + l0 + tap) << 8) + kc;
            As = E_;
            Bx = (const char*)wce + ((size_t)(tap * KOUT + n0) << 8) + kc;
            Bs = E_;
        } else {                 // pos phase: 3 taps x 1 chunk
            int tap = t - 10;
            A  = (const char*)posp + ((size_t)(b * LPP + l0 + tap) << 7);
            As = 128;
            Bx = (const char*)wcp + ((size_t)(tap * KOUT + n0) << 7);
            Bs = 128;
        }
    };

    auto stage = [&](int bf_, const char* A, int As, const char* Bx, int Bs) {
        char* dA = (char*)&sT[bf_][0][0] + tid * 16;
        char* dB = (char*)&sT[bf_][1][0] + tid * 16;
#pragma unroll
        for (int rnd = 0; rnd < 4; rnd++) {          // 8 global_load_lds / wave
            int r = srow + rnd * 32;                 // (r&7)==(srow&7)
            cp16(A  + r * As + ssw, dA + rnd * 4096);
            cp16(Bx + r * Bs + ssw, dB + rnd * 4096);
        }
    };

    auto frag = [&](const unsigned char* base, int row) -> i32x8 {
        const unsigned char* rp = base + row * 128;
        int x  = (row & 7) << 4;
        i32x4 lo = *(const i32x4*)(rp + (((q << 1) << 4) ^ x));
        i32x4 hi = *(const i32x4*)(rp + ((((q << 1) | 1) << 4) ^ x));
        return (i32x8){lo[0], lo[1], lo[2], lo[3], hi[0], hi[1], hi[2], hi[3]};
    };

    auto compute = [&](int bf_) {
        const unsigned char* pA = &sT[bf_][0][0];
        const unsigned char* pB = &sT[bf_][1][0];
        i32x8 af[4];
#pragma unroll
        for (int i = 0; i < 4; i++) af[i] = frag(pA, wr + i * 16 + m);
#pragma unroll
        for (int j = 0; j < 4; j++) {
            i32x8 bfv = frag(pB, wc + j * 16 + m);
#pragma unroll
            for (int i = 0; i < 4; i++)
                // scale bytes 0x7f (e8m0 bias 127) = exactly 1.0
                acc[i][j] = __builtin_amdgcn_mfma_scale_f32_16x16x128_f8f6f4(
                    af[i], bfv, acc[i][j], 0, 0, 0, 0x7f7f7f7f, 0, 0x7f7f7f7f);
        }
    };

    // 2-phase pipeline: 13 K=128 tiles
    {
        const char *A0, *B0; int As0, Bs0;
        bases(0, A0, As0, B0, Bs0);
        stage(0, A0, As0, B0, Bs0);
    }
    int cur = 0;
#pragma unroll 1
    for (int t = 0; t < 13; t++) {
        if (t < 12) {
            const char *A1, *B1; int As1, Bs1;
            bases(t + 1, A1, As1, B1, Bs1);
            stage(cur ^ 1, A1, As1, B1, Bs1);
            // wait only the 8 older loads (tile t); tile t+1's 8 stay in flight
            asm volatile("s_waitcnt vmcnt(8)" ::: "memory");
        } else {
            asm volatile("s_waitcnt vmcnt(0)" ::: "memory");
        }
        __builtin_amdgcn_s_barrier();          // tile t ready for all waves
        __builtin_amdgcn_sched_barrier(0);     // pin: no ds_read hoists above
        compute(cur);
        __builtin_amdgcn_sched_barrier(0);
        __builtin_amdgcn_s_barrier();          // tile t consumed by all waves
        cur ^= 1;
    }

    const float* corrb = corr + b * 2 * KOUT;
#pragma unroll
    for (int j = 0; j < 4; j++) {
        int col = n0 + wc + j * 16 + m;
        float mx = -3.4e38f;
#pragma unroll
        for (int i = 0; i < 4; i++)
#pragma unroll
            for (int r = 0; r < 4; r++) {
                float v = acc[i][j][r] * DESCALE;
                int l = l0 + wr + i * 16 + q * 4 + r;
                if (l == 0)      v -= corrb[col];
                if (l == L_ - 1) v -= corrb[KOUT + col];
                mx = fmaxf(mx, v);
            }
        mx = fmaxf(mx, __shfl_xor(mx, 16, 64));
        mx = fmaxf(mx, __shfl_xor(mx, 32, 64));
        if (q == 0) atomicMax(&pooled[b * KOUT + col], enc_f(mx));
    }
}

// ---------------------------------------------------------------------------
// lin1/lin2: R1's proven pair. lin_fused (R9) regressed ~11 µs — 64 blocks
// starved TLP and serialized 32 dot+reduce chains per wave. The 8192-block
// lin1 keeps all 256 CUs busy; launch overhead is cheaper than lost
// parallelism at this size.
__global__ void lin1_k(const unsigned* __restrict__ pooled,
                       const float* __restrict__ conv_b,
                       const float* __restrict__ lin1_w,
                       const float* __restrict__ lin1_b,
                       float* __restrict__ com) {
    int bid = blockIdx.x;
    int wave = threadIdx.x >> 6, lane = threadIdx.x & 63;
    int b = bid >> 7;
    int h = (bid & 127) * 4 + wave;
    const float* w = lin1_w + (size_t)h * KOUT;
    const unsigned* pb = pooled + b * KOUT;
    float s = 0.f;
#pragma unroll
    for (int i = 0; i < 8; i++) {
        int k = lane + 64 * i;
        s += (dec_f(pb[k]) + conv_b[k]) * w[k];
    }
#pragma unroll
    for (int off = 32; off > 0; off >>= 1) s += __shfl_down(s, off, 64);
    if (lane == 0) com[(size_t)b * COMW + 1536 + h] = tanhf(s + lin1_b[h]);
}

__global__ void lin2_k(const float* __restrict__ com,
                       const float* __restrict__ lin2_w,
                       const float* __restrict__ lin2_b,
                       float* __restrict__ out) {
    int b = blockIdx.x;
    int wave = threadIdx.x >> 6, lane = threadIdx.x & 63;
    int t = blockIdx.y * 4 + wave;
    if (t >= T_) return;
    const float* w = lin2_w + (size_t)t * COMW;
    const float* c = com + (size_t)b * COMW;
    float s = 0.f;
#pragma unroll
    for (int i = 0; i < 32; i++) {
        int k = lane + 64 * i;
        s += c[k] * w[k];
    }
#pragma unroll
    for (int off = 32; off > 0; off >>= 1) s += __shfl_down(s, off, 64);
    if (lane == 0) out[b * T_ + t] = s + lin2_b[t];
}

// ---------------------------------------------------------------------------
extern "C" void kernel_launch(void* const* d_in, const int* in_sizes, int n_in,
                              void* d_out, int out_size, void* d_ws, size_t ws_size,
                              hipStream_t stream) {
    const int*   context = (const int*)d_in[0];
    const int*   sidx    = (const int*)d_in[1];
    const int*   oidx    = (const int*)d_in[2];
    const int*   sdis    = (const int*)d_in[3];
    const int*   odis    = (const int*)d_in[4];
    const float* etab    = (const float*)d_in[5];
    const float* ptab    = (const float*)d_in[6];
    const float* conv_w  = (const float*)d_in[7];
    const float* conv_b  = (const float*)d_in[8];
    const float* lin1_w  = (const float*)d_in[9];
    const float* lin1_b  = (const float*)d_in[10];
    const float* lin2_w  = (const float*)d_in[11];
    const float* lin2_b  = (const float*)d_in[12];
    float* out = (float*)d_out;

    char* ws = (char*)d_ws;
    size_t off = 0;
    unsigned char* embp = (unsigned char*)(ws + off);
    off += (size_t)B_ * LE * E_;                 // 8.45 MB (fp8)
    off = (off + 255) & ~(size_t)255;
    unsigned char* posp = (unsigned char*)(ws + off);
    off += (size_t)B_ * LPP * 128;               // 4.2 MB (fp8)
    off = (off + 255) & ~(size_t)255;
    unsigned char* wce = (unsigned char*)(ws + off);
    off += (size_t)5 * KOUT * E_;                // 655 KB (fp8)
    off = (off + 255) & ~(size_t)255;
    unsigned char* wcp = (unsigned char*)(ws + off);
    off += (size_t)3 * KOUT * 128;               // 197 KB (fp8)
    off = (off + 255) & ~(size_t)255;
    float* corr = (float*)(ws + off);
    off += (size_t)B_ * 2 * KOUT * 4;            // 256 KB
    off = (off + 255) & ~(size_t)255;
    unsigned* pooled = (unsigned*)(ws + off);
    off += (size_t)B_ * KOUT * 4;                // 128 KB
    off = (off + 255) & ~(size_t)255;
    float* com = (float*)(ws + off);
    off += (size_t)B_ * COMW * 4;                // 512 KB

    prep<<<dim3(SEC_END), dim3(256), 0, stream>>>(
        conv_w, context, sidx, oidx, sdis, odis, etab, ptab,
        wce, wcp, embp, posp, corr, com, pooled);
    conv_gemm_pool<<<dim3(256, 4), dim3(256), 0, stream>>>(embp, posp, wce, wcp, corr, pooled);
    lin1_k<<<dim3(8192), dim3(256), 0, stream>>>(pooled, conv_b, lin1_w, lin1_b, com);
    lin2_k<<<dim3(B_, 14), dim3(256), 0, stream>>>(com, lin2_w, lin2_b, out);
}